// Round 5
// baseline (531.589 us; speedup 1.0000x reference)
//
#include <hip/hip_runtime.h>

typedef short short8 __attribute__((ext_vector_type(8)));
typedef short short4v __attribute__((ext_vector_type(4)));
typedef float floatx16 __attribute__((ext_vector_type(16)));
typedef float floatx4 __attribute__((ext_vector_type(4)));

#define ROWS 81
#define CDIM 256
// LDS layout (143 KB total -> 1 block/CU on 160 KB LDS)
#define XT   0          // x tile bf16 [81][256], token-major rows r=m*9+p, swizzle (r&15)<<4, stride 512B
#define RAW  41472      // raw f32 x tile [81][256], linear (gload_lds target), 82944 B
#define QOFF 124416     // q bf16 [81][128... 96 rows x 128 h], stride 256B, swizzle (r&15)<<4
#define SC   145152     // scores f32 [16][16]
#define AB   146176     // attn bf16 [16][16]
#define TOT  146688

typedef const __attribute__((address_space(1))) unsigned int* gas_ptr;
typedef __attribute__((address_space(3))) unsigned int* las_ptr;
#define GLOAD16(g, l) __builtin_amdgcn_global_load_lds((gas_ptr)(g), (las_ptr)(l), 16, 0, 0)

__device__ __forceinline__ unsigned short f2bf(float f) {
    union { float f; unsigned int u; } v; v.f = f;
    return (unsigned short)((v.u + 0x7FFFu + ((v.u >> 16) & 1u)) >> 16);
}

__global__ void wconv_kernel(const float* __restrict__ W,
                             unsigned short* __restrict__ Wb, int n) {
    int i = blockIdx.x * 256 + threadIdx.x;
    if (i < n) Wb[i] = f2bf(W[i]);
}

__global__ __launch_bounds__(1024, 4)
void attn_kernel(const float* __restrict__ x,
                 const unsigned short* __restrict__ Wb,
                 const float* __restrict__ b_fc,
                 const int* __restrict__ block_idx,
                 const int* __restrict__ match_vec,
                 float* __restrict__ out,
                 int B, int nIter)
{
    __shared__ __align__(16) char smem[TOT];
    const int t     = threadIdx.x;
    const int lane  = t & 63;
    const int wave  = t >> 6;       // 0..15
    const int l15   = lane & 15;
    const int kg    = lane >> 4;    // 0..3
    const int l31   = lane & 31;
    const int khalf = lane >> 5;    // 0..1
    const int hgrp  = wave & 7;     // h-column group (16 cols)
    const int rhalf = wave >> 3;    // row half (48 rows)
    const int base  = blockIdx.x * nIter;
    if (base >= B) return;

    // ---- W^T B-fragments + bias (once per 32 batches; L2-hot) ----
    short8 wfrag[8];
    {
        const unsigned short* wr = Wb + (hgrp * 16 + l15) * CDIM + kg * 8;
#pragma unroll
        for (int ks = 0; ks < 8; ++ks)
            wfrag[ks] = *(const short8*)(wr + ks * 32);
    }
    const float bias = b_fc[hgrp * 16 + l15];
    const int swl = l15 << 4;

    // ---- prologue: async DMA x[base] -> RAW (f32, linear) ----
    {
        const float* xb = x + (size_t)base * (ROWS * CDIM);
        for (int u = t; u < 5184; u += 1024)
            GLOAD16(xb + u * 4, smem + RAW + u * 16);
    }
    __syncthreads();    // drains vmcnt: RAW ready

    for (int it = 0; it < nIter; ++it) {
        const int b = base + it;
        if (b >= B) break;
        int cm = 0;
        if (t < 9) cm = match_vec[block_idx[b]];

        // ---- convert RAW f32 -> XT bf16, patch-permute + XOR swizzle ----
        for (int u = t; u < 5184; u += 1024) {
            float4 a = *(const float4*)(smem + RAW + u * 16);
            int gr = u >> 6;                  // uniform per wave
            int c0 = (u & 63) * 4;            // f32 col
            int hh = gr / 9, ww = gr - hh * 9;
            int r = ((hh / 3) * 3 + ww / 3) * 9 + (hh % 3) * 3 + (ww % 3);
            short4v v;
            v[0] = (short)f2bf(a.x); v[1] = (short)f2bf(a.y);
            v[2] = (short)f2bf(a.z); v[3] = (short)f2bf(a.w);
            *(short4v*)(smem + XT + r * 512 + ((c0 * 2) ^ ((r & 15) << 4))) = v;
        }
        __syncthreads();    // XT ready, RAW free

        // ---- issue async DMA of next batch into RAW (no VGPR cost) ----
        if (it + 1 < nIter && b + 1 < B) {
            const float* xn = x + (size_t)(b + 1) * (ROWS * CDIM);
            for (int u = t; u < 5184; u += 1024)
                GLOAD16(xn + u * 4, smem + RAW + u * 16);
        }

        // ---- proj: q[96x128] = x @ W^T; wave -> (rhalf, hgrp), 3 row-tiles ----
        {
            floatx4 acc[3];
#pragma unroll
            for (int i = 0; i < 3; ++i)
#pragma unroll
                for (int j = 0; j < 4; ++j) acc[i][j] = 0.f;
#pragma unroll
            for (int ks = 0; ks < 8; ++ks) {
                int cb = ks * 64 + kg * 16;
#pragma unroll
                for (int tile = 0; tile < 3; ++tile) {
                    int r = rhalf * 48 + tile * 16 + l15;
                    short8 a = *(const short8*)(smem + XT + r * 512 + (cb ^ swl));
                    acc[tile] = __builtin_amdgcn_mfma_f32_16x16x32_bf16(a, wfrag[ks], acc[tile], 0, 0, 0);
                }
            }
            int h2 = (hgrp * 16 + l15) * 2;
#pragma unroll
            for (int tile = 0; tile < 3; ++tile)
#pragma unroll
                for (int reg = 0; reg < 4; ++reg) {
                    int r = rhalf * 48 + tile * 16 + kg * 4 + reg;
                    if (r < ROWS)
                        *(unsigned short*)(smem + QOFF + r * 256 + (h2 ^ ((r & 15) << 4))) =
                            f2bf(acc[tile][reg] + bias);
                }
        }
        __syncthreads();    // q ready (also drains the async DMA — HBM-queue time)

        // ---- gram + softmax fused in wave 0 (same-wave LDS ordering) ----
        if (wave == 0) {
            floatx4 s0, s1, s2, s3;
#pragma unroll
            for (int ii = 0; ii < 4; ++ii) { s0[ii] = 0.f; s1[ii] = 0.f; s2[ii] = 0.f; s3[ii] = 0.f; }
            int nc = (l15 < 9) ? l15 : 8;
#pragma unroll
            for (int s = 0; s < 9; ++s) {
#pragma unroll
                for (int ii = 0; ii < 4; ++ii) {
                    int ks = ii * 9 + s;
                    int k  = ks * 32 + kg * 8;
                    int p  = k >> 7;
                    int h0 = (k & 127) * 2;
                    int row = nc * 9 + p;
                    short8 f = *(const short8*)(smem + QOFF + row * 256 + (h0 ^ ((row & 15) << 4)));
                    floatx4 tmp = __builtin_amdgcn_mfma_f32_16x16x32_bf16(
                        f, f, (ii == 0 ? s0 : ii == 1 ? s1 : ii == 2 ? s2 : s3), 0, 0, 0);
                    if (ii == 0) s0 = tmp; else if (ii == 1) s1 = tmp; else if (ii == 2) s2 = tmp; else s3 = tmp;
                }
            }
            float* sc = (float*)(smem + SC);
#pragma unroll
            for (int reg = 0; reg < 4; ++reg)
                sc[(kg * 4 + reg) * 16 + l15] = s0[reg] + s1[reg] + s2[reg] + s3[reg];

            if (lane < 9) {
                const float scale = 0.029462782549439483f;   // (128*9)^-0.5
                float s[9];
                float mx = -1e30f;
#pragma unroll
                for (int m = 0; m < 9; ++m) {
                    float v = sc[lane * 16 + m] * scale;
                    if (m == lane && cm != 1) v -= 100.f;
                    s[m] = v;
                    mx = fmaxf(mx, v);
                }
                float sum = 0.f;
#pragma unroll
                for (int m = 0; m < 9; ++m) { s[m] = __expf(s[m] - mx); sum += s[m]; }
                float inv = 1.f / sum;
                unsigned short* ab = (unsigned short*)(smem + AB) + lane * 16;
#pragma unroll
                for (int m = 0; m < 9; ++m) ab[m] = f2bf(s[m] * inv);
#pragma unroll
                for (int m = 9; m < 16; ++m) ab[m] = 0;
            }
        }
        __syncthreads();    // attn ready

        // ---- out^T = v^T @ attn^T via 32x32x16; tiles strided over 16 waves ----
        {
            const int n  = l31;
            const int nm = (n < 9) ? n : 0;
            short8 bf = *(const short8*)(smem + AB + nm * 32 + khalf * 16);
            float* ob = out + (size_t)b * (ROWS * CDIM);
            int hh0 = 0, ww0 = 0;
            if (n < 9) { hh0 = (n / 3) * 3; ww0 = (n % 3) * 3; }
            for (int tile = wave; tile < 72; tile += 16) {
                int d = tile * 32 + l31;
                int p = d >> 8, c = d & 255;
                short8 af;
#pragma unroll
                for (int j = 0; j < 8; ++j) {
                    int mm = khalf * 8 + j; if (mm > 8) mm = 8;   // cols m>8 of attn are 0
                    int row = mm * 9 + p;
                    af[j] = *(const short*)(smem + XT + row * 512 + ((c * 2) ^ ((row & 15) << 4)));
                }
                floatx16 dacc;
#pragma unroll
                for (int ii = 0; ii < 16; ++ii) dacc[ii] = 0.f;
                dacc = __builtin_amdgcn_mfma_f32_32x32x16_bf16(af, bf, dacc, 0, 0, 0);
                if (n < 9) {
#pragma unroll
                    for (int q2 = 0; q2 < 4; ++q2) {
                        int d0 = tile * 32 + q2 * 8 + khalf * 4;
                        int p0 = d0 >> 8, c0 = d0 & 255;
                        int gr = (hh0 + p0 / 3) * 9 + (ww0 + p0 % 3);
                        *(float4*)(ob + gr * CDIM + c0) =
                            make_float4(dacc[q2 * 4 + 0], dacc[q2 * 4 + 1],
                                        dacc[q2 * 4 + 2], dacc[q2 * 4 + 3]);
                    }
                }
            }
        }
        __syncthreads();    // XT reads done before next convert overwrites
    }
}

extern "C" void kernel_launch(void* const* d_in, const int* in_sizes, int n_in,
                              void* d_out, int out_size, void* d_ws, size_t ws_size,
                              hipStream_t stream) {
    const float* x    = (const float*)d_in[0];
    const float* W    = (const float*)d_in[1];
    const float* bfc  = (const float*)d_in[2];
    const int*   bidx = (const int*)d_in[3];
    const int*   mvec = (const int*)d_in[4];
    float* outp = (float*)d_out;
    unsigned short* Wb = (unsigned short*)d_ws;

    int nW = in_sizes[1];                       // 128*256
    wconv_kernel<<<(nW + 255) / 256, 256, 0, stream>>>(W, Wb, nW);

    int B = in_sizes[0] / (ROWS * CDIM);        // 8192
    int grid = (B < 256) ? B : 256;
    int nIter = (B + grid - 1) / grid;          // 32
    attn_kernel<<<grid, 1024, 0, stream>>>(x, Wb, bfc, bidx, mvec, outp, B, nIter);
}